// Round 4
// baseline (549.505 us; speedup 1.0000x reference)
//
#include <hip/hip_runtime.h>

// ---------------------------------------------------------------------------
// MHA forward, fp32 I/O (reference is jnp.float32).  S=4096, D=1024, NH=16,
// HD=64.  Internally bf16 MFMA with fp32 accumulate; Q/K/V projections use
// split-bf16 (hi+lo, 3 MFMA passes) to keep absmax well under the 4.3e-3
// threshold; O-projection splits W only (2 passes).  Attention is plain bf16.
// R4: previous NaNs traced to reading f32 inputs as bf16 (mantissa halves
// decode as Inf/NaN)  ->  all global I/O is now float32.
// ---------------------------------------------------------------------------

typedef unsigned short ushort_t;
typedef unsigned short ushort4v __attribute__((ext_vector_type(4)));
typedef unsigned short ushort8 __attribute__((ext_vector_type(8)));
typedef __bf16 bf16x8 __attribute__((ext_vector_type(8)));
typedef float f32x4 __attribute__((ext_vector_type(4)));

#define SEQ 4096
#define DIM 1024
#define NH 16
#define HD 64
#define ATTN_SCALE 0.125f
#define LOG2E 1.4426950408889634f

__device__ inline ushort_t f2b(float f) {
    unsigned int u = __builtin_bit_cast(unsigned int, f);
    u += 0x7fffu + ((u >> 16) & 1u);          // RTNE
    return (ushort_t)(u >> 16);
}
__device__ inline float b2f(ushort_t u) {
    unsigned int v = ((unsigned int)u) << 16;
    return __builtin_bit_cast(float, v);
}
__device__ inline bf16x8 lds_frag(const ushort_t* p) {
    ushort8 t = *(const ushort8*)p;
    return __builtin_bit_cast(bf16x8, t);
}

// ---------------------------------------------------------------------------
// GEMM: C[4096,1024] = A @ W^T + bias.  W is f32, split into bf16 hi+lo.
// A is f32 (split, A_F32=true: 3 MFMA passes) or bf16 (2 passes).
// Output f32 (OUT_F32) or bf16.  Tile 128x64, BK=32, 256 thr = 4 waves 2x2.
// grid = (16, 32) = 512 blocks.
// ---------------------------------------------------------------------------
template <bool A_F32, bool OUT_F32>
__global__ __launch_bounds__(256) void gemm_sp(
    const void* __restrict__ Av, const float* __restrict__ W,
    const float* __restrict__ bias, void* __restrict__ Cv)
{
    __shared__ __align__(16) ushort_t sAhi[128 * 32];
    __shared__ __align__(16) ushort_t sAlo[128 * 32];
    __shared__ __align__(16) ushort_t sBhi[64 * 32];
    __shared__ __align__(16) ushort_t sBlo[64 * 32];

    const int tid  = threadIdx.x;
    const int w    = tid >> 6;
    const int lane = tid & 63;
    const int quad = lane >> 4;
    const int l15  = lane & 15;
    const int wm   = w >> 1;
    const int wn   = w & 1;
    const int m0   = blockIdx.y * 128;
    const int n0   = blockIdx.x * 64;

    f32x4 acc[4][2] = {};

    for (int kt = 0; kt < DIM; kt += 32) {
        __syncthreads();
        if constexpr (A_F32) {
            const float* Af = (const float*)Av;
            for (int r = 0; r < 4; ++r) {
                int c   = r * 256 + tid;       // 0..1023
                int row = c >> 3;              // 0..127 (8 float4 per row)
                int c4  = (c & 7) << 2;        // 0,4,...,28
                f32x4 v = *(const f32x4*)(Af + (size_t)(m0 + row) * DIM + kt + c4);
                ushort4v h, l;
                for (int k = 0; k < 4; ++k) {
                    h[k] = f2b(v[k]);
                    l[k] = f2b(v[k] - b2f(h[k]));
                }
                *(ushort4v*)(sAhi + row * 32 + c4) = h;
                *(ushort4v*)(sAlo + row * 32 + c4) = l;
            }
        } else {
            const ushort_t* Ab = (const ushort_t*)Av;
            for (int r = 0; r < 2; ++r) {
                int c   = r * 256 + tid;       // 0..511
                int row = c >> 2;              // 0..127 (4 ushort8 per row)
                int col = (c & 3) << 3;        // 0,8,16,24
                *(ushort8*)(sAhi + row * 32 + col) =
                    *(const ushort8*)(Ab + (size_t)(m0 + row) * DIM + kt + col);
            }
        }
        for (int r = 0; r < 2; ++r) {
            int c   = r * 256 + tid;           // 0..511
            int row = c >> 3;                  // 0..63
            int c4  = (c & 7) << 2;
            f32x4 v = *(const f32x4*)(W + (size_t)(n0 + row) * DIM + kt + c4);
            ushort4v h, l;
            for (int k = 0; k < 4; ++k) {
                h[k] = f2b(v[k]);
                l[k] = f2b(v[k] - b2f(h[k]));
            }
            *(ushort4v*)(sBhi + row * 32 + c4) = h;
            *(ushort4v*)(sBlo + row * 32 + c4) = l;
        }
        __syncthreads();

        bf16x8 ah[4], al[4], bh[2], bl[2];
        for (int i = 0; i < 4; ++i) {
            ah[i] = lds_frag(sAhi + (wm * 64 + i * 16 + l15) * 32 + quad * 8);
            if constexpr (A_F32)
                al[i] = lds_frag(sAlo + (wm * 64 + i * 16 + l15) * 32 + quad * 8);
        }
        for (int j = 0; j < 2; ++j) {
            bh[j] = lds_frag(sBhi + (wn * 32 + j * 16 + l15) * 32 + quad * 8);
            bl[j] = lds_frag(sBlo + (wn * 32 + j * 16 + l15) * 32 + quad * 8);
        }
        for (int i = 0; i < 4; ++i)
            for (int j = 0; j < 2; ++j) {
                acc[i][j] = __builtin_amdgcn_mfma_f32_16x16x32_bf16(
                    ah[i], bh[j], acc[i][j], 0, 0, 0);
                acc[i][j] = __builtin_amdgcn_mfma_f32_16x16x32_bf16(
                    ah[i], bl[j], acc[i][j], 0, 0, 0);
                if constexpr (A_F32)
                    acc[i][j] = __builtin_amdgcn_mfma_f32_16x16x32_bf16(
                        al[i], bh[j], acc[i][j], 0, 0, 0);
            }
    }

    // epilogue: C/D layout col=lane&15, row=quad*4+reg
    for (int j = 0; j < 2; ++j) {
        int col = n0 + wn * 32 + j * 16 + l15;
        float bj = bias[col];
        for (int i = 0; i < 4; ++i) {
            int row = m0 + wm * 64 + i * 16 + quad * 4;
            for (int r = 0; r < 4; ++r) {
                float val = acc[i][j][r] + bj;
                if constexpr (OUT_F32)
                    ((float*)Cv)[(size_t)(row + r) * DIM + col] = val;
                else
                    ((ushort_t*)Cv)[(size_t)(row + r) * DIM + col] = f2b(val);
            }
        }
    }
}

// ---------------------------------------------------------------------------
// Flash attention, bf16 in (workspace Qp/Kp/Vp), bf16 out (workspace AO).
// One block = (head h, 64 q rows).  4 waves x 16 q rows.  kv tiles of 64.
// LDS stride 72 elems.  grid = (NH, SEQ/64) = 1024 blocks.
// ---------------------------------------------------------------------------
__global__ __launch_bounds__(256) void attn_kernel(
    const ushort_t* __restrict__ Q, const ushort_t* __restrict__ K,
    const ushort_t* __restrict__ V, ushort_t* __restrict__ O)
{
    __shared__ __align__(16) ushort_t sQ[64 * 72];
    __shared__ __align__(16) ushort_t sK[64 * 72];
    __shared__ __align__(16) ushort_t sV[64 * 72];    // transposed: [d][kv]
    __shared__ __align__(16) ushort_t sP[4][16 * 72]; // per-wave P tile

    const int tid  = threadIdx.x;
    const int w    = tid >> 6;
    const int lane = tid & 63;
    const int quad = lane >> 4;
    const int l15  = lane & 15;
    const int h    = blockIdx.x;
    const int q0   = blockIdx.y * 64;

    for (int r = 0; r < 2; ++r) {
        int c = r * 256 + tid;
        int row = c >> 3, d0 = (c & 7) << 3;
        *(ushort8*)(sQ + row * 72 + d0) =
            *(const ushort8*)(Q + (size_t)(q0 + row) * DIM + h * HD + d0);
    }

    f32x4 oacc[4] = {};
    float m_i[4], l_i[4];
    for (int r = 0; r < 4; ++r) { m_i[r] = -1e30f; l_i[r] = 0.f; }

    for (int kv0 = 0; kv0 < SEQ; kv0 += 64) {
        __syncthreads();   // prev tile's reads done (also covers sQ staging)
        for (int r = 0; r < 2; ++r) {
            int c = r * 256 + tid;
            int row = c >> 3, d0 = (c & 7) << 3;
            *(ushort8*)(sK + row * 72 + d0) =
                *(const ushort8*)(K + (size_t)(kv0 + row) * DIM + h * HD + d0);
        }
        for (int r = 0; r < 2; ++r) {
            int d0 = (r * 4 + w) * 8;
            ushort8 vv = *(const ushort8*)(V + (size_t)(kv0 + lane) * DIM + h * HD + d0);
            for (int i = 0; i < 8; ++i)
                sV[(d0 + i) * 72 + lane] = vv[i];
        }
        __syncthreads();

        // S = Q @ K^T
        f32x4 sacc[4] = {};
        bf16x8 qf[2];
        for (int ks = 0; ks < 2; ++ks)
            qf[ks] = lds_frag(sQ + (w * 16 + l15) * 72 + ks * 32 + quad * 8);
        for (int t = 0; t < 4; ++t)
            for (int ks = 0; ks < 2; ++ks) {
                bf16x8 kf = lds_frag(sK + (t * 16 + l15) * 72 + ks * 32 + quad * 8);
                sacc[t] = __builtin_amdgcn_mfma_f32_16x16x32_bf16(
                    qf[ks], kf, sacc[t], 0, 0, 0);
            }

        // online softmax; lane holds rows quad*4+r, cols t*16+l15
        float x[4][4];
        for (int r = 0; r < 4; ++r) {
            float v = -1e30f;
            for (int t = 0; t < 4; ++t) {
                x[t][r] = sacc[t][r] * ATTN_SCALE;
                v = fmaxf(v, x[t][r]);
            }
            for (int off = 1; off < 16; off <<= 1)
                v = fmaxf(v, __shfl_xor(v, off));
            float mnew = fmaxf(m_i[r], v);
            float alpha = exp2f((m_i[r] - mnew) * LOG2E);
            float s = 0.f;
            for (int t = 0; t < 4; ++t) {
                float p = exp2f((x[t][r] - mnew) * LOG2E);
                x[t][r] = p;
                s += p;
            }
            for (int off = 1; off < 16; off <<= 1)
                s += __shfl_xor(s, off);
            l_i[r] = l_i[r] * alpha + s;
            m_i[r] = mnew;
            for (int j = 0; j < 4; ++j) oacc[j][r] *= alpha;
        }

        // P -> LDS (C-layout -> A-fragment layout)
        ushort_t* pw = &sP[w][0];
        for (int t = 0; t < 4; ++t)
            for (int r = 0; r < 4; ++r)
                pw[(quad * 4 + r) * 72 + t * 16 + l15] = f2b(x[t][r]);
        __syncthreads();   // order sP writes before sP reads

        // O += P @ V
        for (int ks = 0; ks < 2; ++ks) {
            bf16x8 pf = lds_frag(pw + l15 * 72 + ks * 32 + quad * 8);
            for (int j = 0; j < 4; ++j) {
                bf16x8 vf = lds_frag(sV + (j * 16 + l15) * 72 + ks * 32 + quad * 8);
                oacc[j] = __builtin_amdgcn_mfma_f32_16x16x32_bf16(
                    pf, vf, oacc[j], 0, 0, 0);
            }
        }
    }

    for (int r = 0; r < 4; ++r) {
        float inv = 1.f / l_i[r];
        int row = q0 + w * 16 + quad * 4 + r;
        for (int j = 0; j < 4; ++j)
            O[(size_t)row * DIM + h * HD + j * 16 + l15] = f2b(oacc[j][r] * inv);
    }
}

// ---------------------------------------------------------------------------
extern "C" void kernel_launch(void* const* d_in, const int* in_sizes, int n_in,
                              void* d_out, int out_size, void* d_ws, size_t ws_size,
                              hipStream_t stream)
{
    const float* q   = (const float*)d_in[0];
    const float* kv  = (const float*)d_in[1];
    const float* q_w = (const float*)d_in[2];
    const float* q_b = (const float*)d_in[3];
    const float* k_w = (const float*)d_in[4];
    const float* k_b = (const float*)d_in[5];
    const float* v_w = (const float*)d_in[6];
    const float* v_b = (const float*)d_in[7];
    const float* o_w = (const float*)d_in[8];
    const float* o_b = (const float*)d_in[9];
    float* out = (float*)d_out;

    ushort_t* Qp = (ushort_t*)d_ws;           // bf16 workspace buffers
    ushort_t* Kp = Qp + (size_t)SEQ * DIM;
    ushort_t* Vp = Kp + (size_t)SEQ * DIM;
    ushort_t* AO = Vp + (size_t)SEQ * DIM;

    dim3 gg(DIM / 64, SEQ / 128);   // (16, 32)
    gemm_sp<true,  false><<<gg, 256, 0, stream>>>(q,  q_w, q_b, Qp);
    gemm_sp<true,  false><<<gg, 256, 0, stream>>>(kv, k_w, k_b, Kp);
    gemm_sp<true,  false><<<gg, 256, 0, stream>>>(kv, v_w, v_b, Vp);
    attn_kernel<<<dim3(NH, SEQ / 64), 256, 0, stream>>>(Qp, Kp, Vp, AO);
    gemm_sp<false, true ><<<gg, 256, 0, stream>>>(AO, o_w, o_b, out);
}

// Round 5
// 411.630 us; speedup vs baseline: 1.3349x; 1.3349x over previous
//
#include <hip/hip_runtime.h>

// ---------------------------------------------------------------------------
// MHA forward, fp32 I/O.  S=4096, D=1024, NH=16, HD=64.
// R5: attention restructured around S^T:  mfma(K,Q) puts q on the C-layout
// column (one q per lane) -> softmax needs only 2 shuffles, no per-row loops;
// P^T written with 4x ds_write_b64 into wave-private LDS and read back as the
// PV B-fragment (no barrier); PV computes O^T = V^T @ P^T; vectorized stores.
// SCALE*LOG2E folded into Q staging.  QKV projections drop the A-lo pass
// (output is bf16-rounded anyway): 2 MFMA passes everywhere.
// ---------------------------------------------------------------------------

typedef unsigned short ushort_t;
typedef unsigned short ushort4v __attribute__((ext_vector_type(4)));
typedef unsigned short ushort8 __attribute__((ext_vector_type(8)));
typedef __bf16 bf16x8 __attribute__((ext_vector_type(8)));
typedef float f32x4 __attribute__((ext_vector_type(4)));

#define SEQ 4096
#define DIM 1024
#define NH 16
#define HD 64
// 0.125 * log2(e): folded into Q so softmax uses exp2 directly
#define QSCALE 0.18033688011112042f

__device__ inline ushort_t f2b(float f) {
    unsigned int u = __builtin_bit_cast(unsigned int, f);
    u += 0x7fffu + ((u >> 16) & 1u);          // RTNE
    return (ushort_t)(u >> 16);
}
__device__ inline float b2f(ushort_t u) {
    unsigned int v = ((unsigned int)u) << 16;
    return __builtin_bit_cast(float, v);
}
__device__ inline bf16x8 lds_frag(const ushort_t* p) {
    ushort8 t = *(const ushort8*)p;
    return __builtin_bit_cast(bf16x8, t);
}

// ---------------------------------------------------------------------------
// GEMM: C[4096,1024] = A @ W^T + bias.  W f32 split into bf16 hi+lo (2 MFMA
// passes).  A is f32 (rounded to bf16 at staging) or already bf16.
// Tile 128x64, BK=32, 256 thr = 4 waves 2x2.  grid = (16,32) = 512 blocks.
// ---------------------------------------------------------------------------
template <bool A_F32, bool OUT_F32>
__global__ __launch_bounds__(256) void gemm_sp(
    const void* __restrict__ Av, const float* __restrict__ W,
    const float* __restrict__ bias, void* __restrict__ Cv)
{
    __shared__ __align__(16) ushort_t sA[128 * 32];
    __shared__ __align__(16) ushort_t sBhi[64 * 32];
    __shared__ __align__(16) ushort_t sBlo[64 * 32];

    const int tid  = threadIdx.x;
    const int w    = tid >> 6;
    const int lane = tid & 63;
    const int quad = lane >> 4;
    const int l15  = lane & 15;
    const int wm   = w >> 1;
    const int wn   = w & 1;
    const int m0   = blockIdx.y * 128;
    const int n0   = blockIdx.x * 64;

    f32x4 acc[4][2] = {};

    for (int kt = 0; kt < DIM; kt += 32) {
        __syncthreads();
        if constexpr (A_F32) {
            const float* Af = (const float*)Av;
            for (int r = 0; r < 4; ++r) {
                int c   = r * 256 + tid;       // 0..1023
                int row = c >> 3;              // 0..127
                int c4  = (c & 7) << 2;
                f32x4 v = *(const f32x4*)(Af + (size_t)(m0 + row) * DIM + kt + c4);
                ushort4v h;
                for (int k = 0; k < 4; ++k) h[k] = f2b(v[k]);
                *(ushort4v*)(sA + row * 32 + c4) = h;
            }
        } else {
            const ushort_t* Ab = (const ushort_t*)Av;
            for (int r = 0; r < 2; ++r) {
                int c   = r * 256 + tid;
                int row = c >> 2;
                int col = (c & 3) << 3;
                *(ushort8*)(sA + row * 32 + col) =
                    *(const ushort8*)(Ab + (size_t)(m0 + row) * DIM + kt + col);
            }
        }
        for (int r = 0; r < 2; ++r) {
            int c   = r * 256 + tid;
            int row = c >> 3;                  // 0..63
            int c4  = (c & 7) << 2;
            f32x4 v = *(const f32x4*)(W + (size_t)(n0 + row) * DIM + kt + c4);
            ushort4v h, l;
            for (int k = 0; k < 4; ++k) {
                h[k] = f2b(v[k]);
                l[k] = f2b(v[k] - b2f(h[k]));
            }
            *(ushort4v*)(sBhi + row * 32 + c4) = h;
            *(ushort4v*)(sBlo + row * 32 + c4) = l;
        }
        __syncthreads();

        bf16x8 af[4], bh[2], bl[2];
        for (int i = 0; i < 4; ++i)
            af[i] = lds_frag(sA + (wm * 64 + i * 16 + l15) * 32 + quad * 8);
        for (int j = 0; j < 2; ++j) {
            bh[j] = lds_frag(sBhi + (wn * 32 + j * 16 + l15) * 32 + quad * 8);
            bl[j] = lds_frag(sBlo + (wn * 32 + j * 16 + l15) * 32 + quad * 8);
        }
        for (int i = 0; i < 4; ++i)
            for (int j = 0; j < 2; ++j) {
                acc[i][j] = __builtin_amdgcn_mfma_f32_16x16x32_bf16(
                    af[i], bh[j], acc[i][j], 0, 0, 0);
                acc[i][j] = __builtin_amdgcn_mfma_f32_16x16x32_bf16(
                    af[i], bl[j], acc[i][j], 0, 0, 0);
            }
    }

    // epilogue: C/D layout col=lane&15, row=quad*4+reg
    for (int j = 0; j < 2; ++j) {
        int col = n0 + wn * 32 + j * 16 + l15;
        float bj = bias[col];
        for (int i = 0; i < 4; ++i) {
            int row = m0 + wm * 64 + i * 16 + quad * 4;
            for (int r = 0; r < 4; ++r) {
                float val = acc[i][j][r] + bj;
                if constexpr (OUT_F32)
                    ((float*)Cv)[(size_t)(row + r) * DIM + col] = val;
                else
                    ((ushort_t*)Cv)[(size_t)(row + r) * DIM + col] = f2b(val);
            }
        }
    }
}

// ---------------------------------------------------------------------------
// Flash attention on S^T.  One block = (head h, 64 q rows); 4 waves x 16 q.
// Per lane: q = w*16 + l15 (one q per lane), kv spread over quad+regs.
// kv tiles of 64.  LDS stride 72.  grid = (NH, SEQ/64) = 1024 blocks.
// ---------------------------------------------------------------------------
__global__ __launch_bounds__(256) void attn_kernel(
    const ushort_t* __restrict__ Q, const ushort_t* __restrict__ K,
    const ushort_t* __restrict__ V, ushort_t* __restrict__ O)
{
    __shared__ __align__(16) ushort_t sQ[64 * 72];    // [q][d], pre-scaled
    __shared__ __align__(16) ushort_t sK[64 * 72];    // [kv][d]
    __shared__ __align__(16) ushort_t sV[64 * 72];    // transposed: [d][kv]
    __shared__ __align__(16) ushort_t sP[4 * 16 * 72];// per-wave P^T [q][kv]

    const int tid  = threadIdx.x;
    const int w    = tid >> 6;
    const int lane = tid & 63;
    const int quad = lane >> 4;
    const int l15  = lane & 15;
    const int h    = blockIdx.x;
    const int q0   = blockIdx.y * 64;

    // stage Q once, folding QSCALE (softmax then uses exp2 directly)
    for (int r = 0; r < 2; ++r) {
        int c = r * 256 + tid;
        int row = c >> 3, d0 = (c & 7) << 3;
        ushort8 v8 = *(const ushort8*)(Q + (size_t)(q0 + row) * DIM + h * HD + d0);
        for (int i = 0; i < 8; ++i) v8[i] = f2b(b2f(v8[i]) * QSCALE);
        *(ushort8*)(sQ + row * 72 + d0) = v8;
    }

    f32x4 oacc[4] = {};            // O^T: oacc[dt][r] at d = dt*16+quad*4+r
    float m_i = -1e30f, l_i = 0.f; // per-lane: this lane's q row

    ushort_t* pw = sP + w * (16 * 72);

    for (int kv0 = 0; kv0 < SEQ; kv0 += 64) {
        __syncthreads();   // prev tile's reads done (also covers sQ staging)
        for (int r = 0; r < 2; ++r) {
            int c = r * 256 + tid;
            int row = c >> 3, d0 = (c & 7) << 3;
            *(ushort8*)(sK + row * 72 + d0) =
                *(const ushort8*)(K + (size_t)(kv0 + row) * DIM + h * HD + d0);
        }
        for (int r = 0; r < 2; ++r) {
            int d0 = (r * 4 + w) * 8;
            ushort8 vv = *(const ushort8*)(V + (size_t)(kv0 + lane) * DIM + h * HD + d0);
            for (int i = 0; i < 8; ++i)
                sV[(d0 + i) * 72 + lane] = vv[i];
        }
        __syncthreads();

        // S^T = K @ Q^T: D[row=kv=quad*4+reg (tile t)][col=q=l15]
        f32x4 sacc[4] = {};
        bf16x8 qf[2];
        for (int ks = 0; ks < 2; ++ks)
            qf[ks] = lds_frag(sQ + (w * 16 + l15) * 72 + ks * 32 + quad * 8);
        for (int t = 0; t < 4; ++t)
            for (int ks = 0; ks < 2; ++ks) {
                bf16x8 kf = lds_frag(sK + (t * 16 + l15) * 72 + ks * 32 + quad * 8);
                sacc[t] = __builtin_amdgcn_mfma_f32_16x16x32_bf16(
                    kf, qf[ks], sacc[t], 0, 0, 0);
            }

        // softmax: all 16 values belong to this lane's q; reduce over regs
        // then across quads (lanes l15, l15+16, l15+32, l15+48)
        float xm = -1e30f;
        for (int t = 0; t < 4; ++t)
            for (int r = 0; r < 4; ++r) xm = fmaxf(xm, sacc[t][r]);
        xm = fmaxf(xm, __shfl_xor(xm, 16));
        xm = fmaxf(xm, __shfl_xor(xm, 32));
        float mnew  = fmaxf(m_i, xm);
        float alpha = exp2f(m_i - mnew);
        float s = 0.f;
        float p[4][4];
        for (int t = 0; t < 4; ++t)
            for (int r = 0; r < 4; ++r) {
                p[t][r] = exp2f(sacc[t][r] - mnew);
                s += p[t][r];
            }
        s += __shfl_xor(s, 16);
        s += __shfl_xor(s, 32);
        l_i = l_i * alpha + s;
        m_i = mnew;
        for (int j = 0; j < 4; ++j) oacc[j] *= alpha;

        // P^T -> wave-private LDS [q=l15][kv], vectorized b64 writes.
        // In-wave write->read ordering via lgkmcnt; no barrier needed.
        for (int t = 0; t < 4; ++t) {
            ushort4v pk;
            for (int r = 0; r < 4; ++r) pk[r] = f2b(p[t][r]);
            *(ushort4v*)(pw + l15 * 72 + t * 16 + quad * 4) = pk;
        }

        // O^T += V^T @ P^T :  A = V^T frag (m=d=l15, k=kv=quad*8+j),
        //                     B = P^T frag (n=q=l15, k=kv=quad*8+j)
        for (int kt = 0; kt < 2; ++kt) {
            bf16x8 pf = lds_frag(pw + l15 * 72 + kt * 32 + quad * 8);
            for (int dt = 0; dt < 4; ++dt) {
                bf16x8 vf = lds_frag(sV + (dt * 16 + l15) * 72 + kt * 32 + quad * 8);
                oacc[dt] = __builtin_amdgcn_mfma_f32_16x16x32_bf16(
                    vf, pf, oacc[dt], 0, 0, 0);
            }
        }
    }

    // epilogue: O^T -> O[q][h*64+d], 8B vector stores
    float inv = 1.f / l_i;
    int qrow = q0 + w * 16 + l15;
    for (int dt = 0; dt < 4; ++dt) {
        ushort4v o4;
        for (int r = 0; r < 4; ++r) o4[r] = f2b(oacc[dt][r] * inv);
        *(ushort4v*)(O + (size_t)qrow * DIM + h * HD + dt * 16 + quad * 4) = o4;
    }
}

// ---------------------------------------------------------------------------
extern "C" void kernel_launch(void* const* d_in, const int* in_sizes, int n_in,
                              void* d_out, int out_size, void* d_ws, size_t ws_size,
                              hipStream_t stream)
{
    const float* q   = (const float*)d_in[0];
    const float* kv  = (const float*)d_in[1];
    const float* q_w = (const float*)d_in[2];
    const float* q_b = (const float*)d_in[3];
    const float* k_w = (const float*)d_in[4];
    const float* k_b = (const float*)d_in[5];
    const float* v_w = (const float*)d_in[6];
    const float* v_b = (const float*)d_in[7];
    const float* o_w = (const float*)d_in[8];
    const float* o_b = (const float*)d_in[9];
    float* out = (float*)d_out;

    ushort_t* Qp = (ushort_t*)d_ws;           // bf16 workspace buffers
    ushort_t* Kp = Qp + (size_t)SEQ * DIM;
    ushort_t* Vp = Kp + (size_t)SEQ * DIM;
    ushort_t* AO = Vp + (size_t)SEQ * DIM;

    dim3 gg(DIM / 64, SEQ / 128);   // (16, 32)
    gemm_sp<true,  false><<<gg, 256, 0, stream>>>(q,  q_w, q_b, Qp);
    gemm_sp<true,  false><<<gg, 256, 0, stream>>>(kv, k_w, k_b, Kp);
    gemm_sp<true,  false><<<gg, 256, 0, stream>>>(kv, v_w, v_b, Vp);
    attn_kernel<<<dim3(NH, SEQ / 64), 256, 0, stream>>>(Qp, Kp, Vp, AO);
    gemm_sp<false, true ><<<gg, 256, 0, stream>>>(AO, o_w, o_b, out);
}